// Round 6
// baseline (480.633 us; speedup 1.0000x reference)
//
#include <hip/hip_runtime.h>
#include <hip/hip_bf16.h>

namespace {

constexpr int T = 4096, N = 256, U = 128, K = 32, P = 128;
constexpr int NK = N * K;           // 8192 scan lanes
constexpr int CL = 16;              // chunk length = block timestep span
constexpr int NCH = T / CL;         // 256 chunks total
constexpr int NG = NCH / 8;         // 32 carry groups (8 chunks each)
constexpr int TB = 16;              // timesteps per block in bgemm (== CL)

typedef __attribute__((ext_vector_type(8))) short short8;   // 8 bf16
typedef __attribute__((ext_vector_type(4))) float f32x4;
typedef __attribute__((address_space(3))) unsigned lds_u32;
typedef __attribute__((address_space(1))) const unsigned glb_u32;

__device__ __forceinline__ unsigned short f2bf(float f) {
  union { float f; unsigned u; } v; v.f = f;
  unsigned r = v.u + 0x7FFFu + ((v.u >> 16) & 1u);   // RNE
  return (unsigned short)(r >> 16);
}
__device__ __forceinline__ float bf2f(unsigned short s) {
  union { unsigned u; float f; } v; v.u = ((unsigned)s) << 16;
  return v.f;
}
__device__ __forceinline__ short8 ld8(const unsigned short* p) {
  return *reinterpret_cast<const short8*>(p);
}
// async global->LDS, 16 B per lane; LDS dest = wave-uniform base + lane*16
__device__ __forceinline__ void dma16(const unsigned* g, unsigned* l) {
  __builtin_amdgcn_global_load_lds((glb_u32*)g, (lds_u32*)l, 16, 0, 0);
}
__device__ __forceinline__ void csq(float& pr, float& pi) {  // complex square
  float nr = pr * pr - pi * pi, ni = 2.f * pr * pi; pr = nr; pi = ni;
}

// Swizzled storage index (dwords) of logical element (k,n) within a t-slice.
__device__ __forceinline__ int zswz(int k, int n) {
  int n8 = n >> 3, j = n & 7;
  return k * 256 + ((n8 ^ (k & 7)) << 3) + (j ^ (((k >> 3) & 1) << 2));
}

// a = dwords for n8*8+{0..3}, b = n8*8+{4..7}; each dword packs (re|im) bf16
__device__ __forceinline__ void unpackAB(uint4 a, uint4 b, short8& re, short8& im) {
  union { short8 v; unsigned u[4]; } r, i;
  r.u[0] = (a.x & 0xFFFFu) | (a.y << 16);
  i.u[0] = (a.x >> 16)     | (a.y & 0xFFFF0000u);
  r.u[1] = (a.z & 0xFFFFu) | (a.w << 16);
  i.u[1] = (a.z >> 16)     | (a.w & 0xFFFF0000u);
  r.u[2] = (b.x & 0xFFFFu) | (b.y << 16);
  i.u[2] = (b.x >> 16)     | (b.y & 0xFFFF0000u);
  r.u[3] = (b.z & 0xFFFFu) | (b.w << 16);
  i.u[3] = (b.z >> 16)     | (b.w & 0xFFFF0000u);
  re = r.v; im = i.v;
}

// ---- cast params: B,C,D -> bf16 (Cim negated); A -> swizzled-lane-order fp32
__global__ __launch_bounds__(256) void k_params(
    const float* Are, const float* Aim, const float* Bre, const float* Bim,
    const float* Cre, const float* Cim, const float* D,
    unsigned short* bre, unsigned short* bim, unsigned short* cre,
    unsigned short* cimn, unsigned short* dbf, float* atre, float* atim) {
  int idx = blockIdx.x * 256 + threadIdx.x;
  int stride = gridDim.x * 256;
  for (int i = idx; i < N * U; i += stride) { bre[i] = f2bf(Bre[i]); bim[i] = f2bf(Bim[i]); }
  for (int i = idx; i < P * N; i += stride) { cre[i] = f2bf(Cre[i]); cimn[i] = f2bf(-Cim[i]); }
  for (int i = idx; i < P * U; i += stride) { dbf[i] = f2bf(D[i]); }
  for (int i = idx; i < NK; i += stride) {
    // i is the STORAGE index; invert zswz (XOR is involutive)
    int k = i >> 8, r = i & 255;
    int n8 = (r >> 3) ^ (k & 7);
    int j  = (r & 7) ^ (((k >> 3) & 1) << 2);
    int n = n8 * 8 + j;
    atre[i] = Are[n * K + k];
    atim[i] = Aim[n * K + k];
  }
}

// ---- x (T,U,K) fp32 -> xT (T,K,U) bf16 (u contiguous), via LDS transpose
__global__ __launch_bounds__(256) void k_castx(const float* x, unsigned* xTu) {
  __shared__ float lds[U * 33];            // rows u, padded stride 33
  int t = blockIdx.x, tid = threadIdx.x;
  const float* xt = x + (size_t)t * (U * K);
#pragma unroll
  for (int it = 0; it < 16; it++) {
    int idx = it * 256 + tid;
    int u = idx >> 5, k = idx & 31;
    lds[u * 33 + k] = xt[idx];
  }
  __syncthreads();
  unsigned* dst = xTu + (size_t)t * (K * U / 2);
#pragma unroll
  for (int it = 0; it < 8; it++) {
    int k = it * 4 + (tid >> 6);
    int up = tid & 63;
    float f0 = lds[(2 * up) * 33 + k];
    float f1 = lds[(2 * up + 1) * 33 + k];
    dst[k * 64 + up] = (unsigned)f2bf(f0) | ((unsigned)f2bf(f1) << 16);
  }
}

// ---- zbuf[tl][swz(k,n)] (packed bf16 re|im) = B @ x_t, PLUS in-register
//      chunk-local scan on the just-computed (bf16-rounded) z -> cend.
//      512 threads / 8 waves; wave w owns n-tiles (w*2+nt)*16; TB=CL=16 so
//      one block = one chunk.  Scan state lives in the same lanes as the
//      MFMA C/D fragments (layout is t-invariant), so the scan is pure ILP
//      under the MFMA stream.  cend is bit-identical to old k_scanA output.
__global__ __launch_bounds__(512)
__attribute__((amdgpu_waves_per_eu(2, 2)))
void k_bgemm(const unsigned short* xT, const unsigned short* bre,
             const unsigned short* bim, const float* atre, const float* atim,
             unsigned* zbuf, float2* cend, int t0, int c0, int wr_cend) {
  int blk = blockIdx.x, tid = threadIdx.x;
  int w = tid >> 6, l = tid & 63, lq = l >> 4, lr = l & 15;
  short8 Bf_re[4][2], Bf_im[4][2];   // [s][nt] -> 64 VGPRs
#pragma unroll
  for (int s = 0; s < 4; s++)
#pragma unroll
    for (int nt = 0; nt < 2; nt++) {
      int n0 = (w * 2 + nt) * 16;
      Bf_re[s][nt] = ld8(bre + (n0 + lr) * U + s * 32 + lq * 8);
      Bf_im[s][nt] = ld8(bim + (n0 + lr) * U + s * 32 + lq * 8);
    }
  // scan A + state for this thread's 16 fragment elements
  float ar[16], ai[16], sr[16], si[16];
#pragma unroll
  for (int mt = 0; mt < 2; mt++)
#pragma unroll
    for (int nt = 0; nt < 2; nt++)
#pragma unroll
      for (int r = 0; r < 4; r++) {
        int e = mt * 8 + nt * 4 + r;
        int krow = mt * 16 + lq * 4 + r;
        int n = (w * 2 + nt) * 16 + lr;
        int idx = zswz(krow, n);
        ar[e] = atre[idx]; ai[e] = atim[idx];
        sr[e] = 0.f; si[e] = 0.f;
      }
#pragma unroll
  for (int tl = 0; tl < TB; tl++) {
    int tloc = blk * TB + tl;
    const unsigned short* xrow = xT + (size_t)(t0 + tloc) * (K * U);
    short8 af[4][2];
#pragma unroll
    for (int s = 0; s < 4; s++) {
      af[s][0] = ld8(xrow + lr * U + s * 32 + lq * 8);
      af[s][1] = ld8(xrow + (16 + lr) * U + s * 32 + lq * 8);
    }
    f32x4 accre[2][2], accim[2][2];
#pragma unroll
    for (int a = 0; a < 2; a++)
#pragma unroll
      for (int b = 0; b < 2; b++) { accre[a][b] = (f32x4)0.f; accim[a][b] = (f32x4)0.f; }
#pragma unroll
    for (int s = 0; s < 4; s++)
#pragma unroll
      for (int nt = 0; nt < 2; nt++)
#pragma unroll
        for (int mt = 0; mt < 2; mt++) {
          accre[mt][nt] = __builtin_amdgcn_mfma_f32_16x16x32_bf16(af[s][mt], Bf_re[s][nt], accre[mt][nt], 0, 0, 0);
          accim[mt][nt] = __builtin_amdgcn_mfma_f32_16x16x32_bf16(af[s][mt], Bf_im[s][nt], accim[mt][nt], 0, 0, 0);
        }
    unsigned* dst = zbuf + (size_t)tloc * NK;
#pragma unroll
    for (int mt = 0; mt < 2; mt++)
#pragma unroll
      for (int nt = 0; nt < 2; nt++) {
        int n0 = (w * 2 + nt) * 16;
#pragma unroll
        for (int r = 0; r < 4; r++) {
          int krow = mt * 16 + lq * 4 + r;
          unsigned dv = (unsigned)f2bf(accre[mt][nt][r]) |
                        ((unsigned)f2bf(accim[mt][nt][r]) << 16);
          dst[zswz(krow, n0 + lr)] = dv;
          // scan on the bf16-rounded value (bit-compatible with old scanA)
          int e = mt * 8 + nt * 4 + r;
          float ur = bf2f((unsigned short)(dv & 0xFFFFu));
          float ui = bf2f((unsigned short)(dv >> 16));
          float nr2 = ar[e] * sr[e] - ai[e] * si[e] + ur;
          float ni2 = ar[e] * si[e] + ai[e] * sr[e] + ui;
          sr[e] = nr2; si[e] = ni2;
        }
      }
  }
  if (wr_cend) {
    float2* ce = cend + (size_t)(c0 + blk) * NK;
#pragma unroll
    for (int mt = 0; mt < 2; mt++)
#pragma unroll
      for (int nt = 0; nt < 2; nt++)
#pragma unroll
        for (int r = 0; r < 4; r++) {
          int e = mt * 8 + nt * 4 + r;
          int krow = mt * 16 + lq * 4 + r;
          int n = (w * 2 + nt) * 16 + lr;
          ce[zswz(krow, n)] = make_float2(sr[e], si[e]);
        }
  }
}

// ---- carry hierarchy over cend[NCH][NK] (storage-lane order, A = atre/atim).
// g-level: aggregate of each group of 8 chunk-ends, multiplier a^CL (= a^16)
__global__ __launch_bounds__(256) void k_carryg(const float2* cend, const float* atre,
                                                const float* atim, float2* gagg) {
  int bid = blockIdx.x;
  int g = bid >> 5;
  int lane = (bid & 31) * 256 + threadIdx.x;
  float pr = atre[lane], pi = atim[lane];
#pragma unroll
  for (int i = 0; i < 4; i++) csq(pr, pi);   // a^16
  float agr = 0.f, agi = 0.f;
#pragma unroll
  for (int j = 0; j < 8; j++) {
    float2 e = cend[(size_t)(g * 8 + j) * NK + lane];
    float nr = pr * agr - pi * agi + e.x;
    float ni = pr * agi + pi * agr + e.y;
    agr = nr; agi = ni;
  }
  gagg[(size_t)g * NK + lane] = make_float2(agr, agi);
}

// b-level: exclusive scan across NG groups, multiplier a^(CL*8) = a^128; in place
__global__ __launch_bounds__(256) void k_carryb(float2* gagg, const float* atre,
                                                const float* atim) {
  int lane = blockIdx.x * 256 + threadIdx.x;
  float pr = atre[lane], pi = atim[lane];
#pragma unroll
  for (int i = 0; i < 7; i++) csq(pr, pi);   // a^128
  float cr = 0.f, ci = 0.f;
  for (int gg = 0; gg < NG / 8; gg++) {
    float2 buf[8];
#pragma unroll
    for (int j = 0; j < 8; j++) buf[j] = gagg[(size_t)(gg * 8 + j) * NK + lane];
#pragma unroll
    for (int j = 0; j < 8; j++) {
      gagg[(size_t)(gg * 8 + j) * NK + lane] = make_float2(cr, ci);
      float nr = pr * cr - pi * ci + buf[j].x;
      float ni = pr * ci + pi * cr + buf[j].y;
      cr = nr; ci = ni;
    }
  }
}

// f-level: expand group carries to per-chunk carry-ins; cend -> carry-in, in place
__global__ __launch_bounds__(256) void k_carryf(float2* cend, const float* atre,
                                                const float* atim, const float2* gagg) {
  int bid = blockIdx.x;
  int g = bid >> 5;
  int lane = (bid & 31) * 256 + threadIdx.x;
  float pr = atre[lane], pi = atim[lane];
#pragma unroll
  for (int i = 0; i < 4; i++) csq(pr, pi);   // a^16
  float2 c = gagg[(size_t)g * NK + lane];
  float cr = c.x, ci = c.y;
#pragma unroll
  for (int j = 0; j < 8; j++) {
    size_t off = (size_t)(g * 8 + j) * NK + lane;
    float2 e = cend[off];
    cend[off] = make_float2(cr, ci);
    float nr = pr * cr - pi * ci + e.x;
    float ni = pr * ci + pi * cr + e.y;
    cr = nr; ci = ni;
  }
}

// ---- fused replay-scan + output, 3-slice LDS ring, ONE raw barrier per
//      timestep, counted vmcnt (never drained):
//        iter t: xfr(t) loads | vmcnt(20) -> own DMA(t) done |
//                scan buf[t%3] (own 16B regions = own dma16 lanes) |
//                lgkmcnt(0); s_barrier  (scan visible; old readers drained) |
//                issue DMA(t+2) -> buf[(t+2)%3] | MFMA from buf[t%3] | stores
//      DMA prefetch stays 2 slices deep across the barrier (T3/T4 pattern).
__global__ __launch_bounds__(512)
__attribute__((amdgpu_waves_per_eu(2, 2)))
void k_scout(const unsigned* zbuf, const float* atre, const float* atim,
             const float2* cend,
             const unsigned short* cre, const unsigned short* cimn,
             const unsigned short* dbf, const unsigned short* xT,
             float* out, int t0, int gc0) {
  __shared__ unsigned ldsz[3][NK];   // 3 x 32 KB ring
  int blk = blockIdx.x, tid = threadIdx.x;
  int w = tid >> 6, l = tid & 63, lq = l >> 4, lr = l & 15;
  int h = (lr >> 3) & 1;
  // hoist C/D fragments: wave w owns p-tile w*16
  short8 Cf_re[8], Cf_im[8];         // 64 VGPRs
#pragma unroll
  for (int s = 0; s < 8; s++) {
    int p = w * 16 + lr;
    Cf_re[s] = ld8(cre  + p * N + s * 32 + lq * 8);
    Cf_im[s] = ld8(cimn + p * N + s * 32 + lq * 8);
  }
  short8 Df[4];                      // 16 VGPRs
#pragma unroll
  for (int s = 0; s < 4; s++) {
    int p = w * 16 + lr;
    Df[s] = ld8(dbf + p * U + s * 32 + lq * 8);
  }
  // scan state + A for this thread's 16 storage dwords (it*2048 + tid*4 + j)
  float ar[16], ai[16], sr[16], si[16];
  int gc = gc0 + blk;
#pragma unroll
  for (int it = 0; it < 4; it++)
#pragma unroll
    for (int j = 0; j < 4; j++) {
      int idx = it * 2048 + tid * 4 + j;
      int e = it * 4 + j;
      ar[e] = atre[idx]; ai[e] = atim[idx];
      float2 c0 = cend[(size_t)gc * NK + idx];   // carry-in (exclusive)
      sr[e] = c0.x; si[e] = c0.y;
    }
  // prologue: DMA slices 0 and 1 into ring buffers 0,1
  const unsigned* zch = zbuf + (size_t)(blk * CL) * NK;
#pragma unroll
  for (int it = 0; it < 4; it++)
    dma16(zch + it * 2048 + tid * 4, &ldsz[0][it * 2048 + tid * 4]);
#pragma unroll
  for (int it = 0; it < 4; it++)
    dma16(zch + NK + it * 2048 + tid * 4, &ldsz[1][it * 2048 + tid * 4]);

  int bc = 0;                        // ring slot of slice tl
  for (int tl = 0; tl < CL; tl++) {
    int t = t0 + blk * CL + tl;      // global t
    // x fragments first (counted in the vmcnt budget below)
    const unsigned short* xt = xT + (size_t)t * (K * U);
    short8 xfr[4][2];
#pragma unroll
    for (int s = 0; s < 4; s++)
#pragma unroll
      for (int kt = 0; kt < 2; kt++)
        xfr[s][kt] = ld8(xt + (kt * 16 + lr) * U + s * 32 + lq * 8);
    // own DMA(tl) complete; allow {xfr 8, stores(t-1) 8, DMA(tl+1) 4} in flight
    if (tl == 0) { asm volatile("s_waitcnt vmcnt(12)" ::: "memory"); }
    else         { asm volatile("s_waitcnt vmcnt(20)" ::: "memory"); }
    // ---- scan: update this thread's 16 dwords of slice tl in place
    unsigned* zl = &ldsz[bc][0];
#pragma unroll
    for (int it = 0; it < 4; it++) {
      unsigned* p4 = zl + it * 2048 + tid * 4;
      uint4 v = *reinterpret_cast<const uint4*>(p4);
      unsigned d0 = v.x, d1 = v.y, d2 = v.z, d3 = v.w;
#pragma unroll
      for (int j = 0; j < 4; j++) {
        unsigned dv = (j == 0) ? d0 : (j == 1) ? d1 : (j == 2) ? d2 : d3;
        int e = it * 4 + j;
        float ur = bf2f((unsigned short)(dv & 0xFFFFu));
        float ui = bf2f((unsigned short)(dv >> 16));
        float nr = ar[e] * sr[e] - ai[e] * si[e] + ur;
        float ni = ar[e] * si[e] + ai[e] * sr[e] + ui;
        sr[e] = nr; si[e] = ni;
        dv = (unsigned)f2bf(nr) | ((unsigned)f2bf(ni) << 16);
        if (j == 0) d0 = dv; else if (j == 1) d1 = dv; else if (j == 2) d2 = dv; else d3 = dv;
      }
      uint4 o; o.x = d0; o.y = d1; o.z = d2; o.w = d3;
      *reinterpret_cast<uint4*>(p4) = o;
    }
    // scan writes drained, then single cross-wave barrier
    asm volatile("s_waitcnt lgkmcnt(0)" ::: "memory");
    __builtin_amdgcn_s_barrier();
    __builtin_amdgcn_sched_barrier(0);
    // async prefetch slice tl+2 into ring slot (bc+2)%3 (readers drained above)
    if (tl + 2 < CL) {
      int bn = bc + 2; if (bn >= 3) bn -= 3;
      const unsigned* zn = zbuf + (size_t)(blk * CL + tl + 2) * NK;
#pragma unroll
      for (int it = 0; it < 4; it++)
        dma16(zn + it * 2048 + tid * 4, &ldsz[bn][it * 2048 + tid * 4]);
    }
    // ---- output MFMAs from the states slice
    f32x4 acc[2];
    acc[0] = (f32x4)0.f; acc[1] = (f32x4)0.f;
    const unsigned* zs = &ldsz[bc][0];
#pragma unroll
    for (int s = 0; s < 8; s++) {
      short8 bfr[2], bfi[2];
#pragma unroll
      for (int kt = 0; kt < 2; kt++) {
        int k = kt * 16 + lr;
        int n8 = s * 4 + lq;
        const uint4* qp = reinterpret_cast<const uint4*>(zs + k * 256 + ((n8 ^ (k & 7)) << 3));
        uint4 a = qp[h], b = qp[h ^ 1];
        unpackAB(a, b, bfr[kt], bfi[kt]);
      }
#pragma unroll
      for (int kt = 0; kt < 2; kt++) {
        acc[kt] = __builtin_amdgcn_mfma_f32_16x16x32_bf16(Cf_re[s], bfr[kt], acc[kt], 0, 0, 0);
        acc[kt] = __builtin_amdgcn_mfma_f32_16x16x32_bf16(Cf_im[s], bfi[kt], acc[kt], 0, 0, 0);
      }
    }
#pragma unroll
    for (int s = 0; s < 4; s++)
#pragma unroll
      for (int kt = 0; kt < 2; kt++)
        acc[kt] = __builtin_amdgcn_mfma_f32_16x16x32_bf16(Df[s], xfr[s][kt], acc[kt], 0, 0, 0);
    float* ot = out + (size_t)t * (P * K);
#pragma unroll
    for (int kt = 0; kt < 2; kt++)
#pragma unroll
      for (int r = 0; r < 4; r++) {
        int p = w * 16 + lq * 4 + r;
        int k = kt * 16 + lr;
        ot[p * K + k] = acc[kt][r];
      }
    bc = bc + 1; if (bc >= 3) bc -= 3;
  }
}

}  // namespace

extern "C" void kernel_launch(void* const* d_in, const int* in_sizes, int n_in,
                              void* d_out, int out_size, void* d_ws, size_t ws_size,
                              hipStream_t stream) {
  const float* x   = (const float*)d_in[0];
  const float* Are = (const float*)d_in[1];
  const float* Aim = (const float*)d_in[2];
  const float* Bre = (const float*)d_in[3];
  const float* Bim = (const float*)d_in[4];
  const float* Cre = (const float*)d_in[5];
  const float* Cim = (const float*)d_in[6];
  const float* D   = (const float*)d_in[7];
  float* out = (float*)d_out;

  auto al = [](size_t x_) { return (x_ + 255) & ~(size_t)255; };
  const size_t fixed = al((size_t)T * K * U * 2)      // xT
                     + al((size_t)NCH * NK * 8)       // cend
                     + al((size_t)NG * NK * 8)        // gagg
                     + 2 * al((size_t)N * U * 2)      // bre,bim
                     + 2 * al((size_t)P * N * 2)      // cre,cimn
                     + al((size_t)P * U * 2)          // dbf
                     + 2 * al((size_t)NK * 4);        // atre,atim
  int S = 64;
  for (int s : {1, 2, 4, 8, 16, 32, 64}) {
    if (fixed + al((size_t)(T / s) * NK * 4) <= ws_size) { S = s; break; }
  }
  const int TS = T / S;        // timesteps per stage
  const int CS = NCH / S;      // chunks per stage

  char* w = (char*)d_ws;
  auto alloc = [&](size_t bytes) { void* p = (void*)w; w += (bytes + 255) & ~(size_t)255; return p; };
  unsigned* zbuf       = (unsigned*)alloc((size_t)TS * NK * 4);
  unsigned* xTu        = (unsigned*)alloc((size_t)T * K * U * 2);
  float2* cend         = (float2*)alloc((size_t)NCH * NK * 8);
  float2* gagg         = (float2*)alloc((size_t)NG * NK * 8);
  unsigned short* bre  = (unsigned short*)alloc((size_t)N * U * 2);
  unsigned short* bim  = (unsigned short*)alloc((size_t)N * U * 2);
  unsigned short* cre  = (unsigned short*)alloc((size_t)P * N * 2);
  unsigned short* cimn = (unsigned short*)alloc((size_t)P * N * 2);
  unsigned short* dbf  = (unsigned short*)alloc((size_t)P * U * 2);
  float* atre          = (float*)alloc((size_t)NK * 4);
  float* atim          = (float*)alloc((size_t)NK * 4);

  k_params<<<64, 256, 0, stream>>>(Are, Aim, Bre, Bim, Cre, Cim, D,
                                   bre, bim, cre, cimn, dbf, atre, atim);
  k_castx<<<T, 256, 0, stream>>>(x, xTu);

  const unsigned short* xT16 = (const unsigned short*)xTu;
  // pass 1: B@x GEMM with fused chunk-local scan (cend written in-kernel)
  for (int q = 0; q < S; q++)
    k_bgemm<<<TS / TB, 512, 0, stream>>>(xT16, bre, bim, atre, atim,
                                         zbuf, cend, q * TS, q * CS, 1);
  // cross-chunk carries, hierarchical (groups of 8 chunks, then NG groups)
  k_carryg<<<NG * 32, 256, 0, stream>>>(cend, atre, atim, gagg);
  k_carryb<<<NK / 256, 256, 0, stream>>>(gagg, atre, atim);
  k_carryf<<<NG * 32, 256, 0, stream>>>(cend, atre, atim, gagg);
  // pass 2: fused replay-scan + output (states never touch HBM)
  for (int q = 0; q < S; q++) {
    if (S > 1)  // zbuf was overwritten by later stages; recompute (no cend!)
      k_bgemm<<<TS / TB, 512, 0, stream>>>(xT16, bre, bim, atre, atim,
                                           zbuf, cend, q * TS, q * CS, 0);
    k_scout<<<TS / CL, 512, 0, stream>>>(zbuf, atre, atim, cend,
                                         cre, cimn, dbf, xT16, out, q * TS, q * CS);
  }
}

// Round 7
// 272.296 us; speedup vs baseline: 1.7651x; 1.7651x over previous
//
#include <hip/hip_runtime.h>
#include <hip/hip_bf16.h>

namespace {

constexpr int T = 4096, N = 256, U = 128, K = 32, P = 128;
constexpr int NK = N * K;           // 8192 scan lanes
constexpr int CL = 16;              // chunk length = k_scout block timestep span
constexpr int NCH = T / CL;         // 256 chunks total
constexpr int NG = NCH / 8;         // 32 carry groups (8 chunks each)
constexpr int TB = 8;               // timesteps per block in bgemm

typedef __attribute__((ext_vector_type(8))) short short8;   // 8 bf16
typedef __attribute__((ext_vector_type(4))) float f32x4;
typedef __attribute__((address_space(3))) unsigned lds_u32;
typedef __attribute__((address_space(1))) const unsigned glb_u32;

__device__ __forceinline__ unsigned short f2bf(float f) {
  union { float f; unsigned u; } v; v.f = f;
  unsigned r = v.u + 0x7FFFu + ((v.u >> 16) & 1u);   // RNE
  return (unsigned short)(r >> 16);
}
__device__ __forceinline__ float bf2f(unsigned short s) {
  union { unsigned u; float f; } v; v.u = ((unsigned)s) << 16;
  return v.f;
}
__device__ __forceinline__ short8 ld8(const unsigned short* p) {
  return *reinterpret_cast<const short8*>(p);
}
// async global->LDS, 16 B per lane; LDS dest = wave-uniform base + lane*16
__device__ __forceinline__ void dma16(const unsigned* g, unsigned* l) {
  __builtin_amdgcn_global_load_lds((glb_u32*)g, (lds_u32*)l, 16, 0, 0);
}
__device__ __forceinline__ void csq(float& pr, float& pi) {  // complex square
  float nr = pr * pr - pi * pi, ni = 2.f * pr * pi; pr = nr; pi = ni;
}

// Swizzled storage index (dwords) of logical element (k,n) within a t-slice.
__device__ __forceinline__ int zswz(int k, int n) {
  int n8 = n >> 3, j = n & 7;
  return k * 256 + ((n8 ^ (k & 7)) << 3) + (j ^ (((k >> 3) & 1) << 2));
}

// a = dwords for n8*8+{0..3}, b = n8*8+{4..7}; each dword packs (re|im) bf16
__device__ __forceinline__ void unpackAB(uint4 a, uint4 b, short8& re, short8& im) {
  union { short8 v; unsigned u[4]; } r, i;
  r.u[0] = (a.x & 0xFFFFu) | (a.y << 16);
  i.u[0] = (a.x >> 16)     | (a.y & 0xFFFF0000u);
  r.u[1] = (a.z & 0xFFFFu) | (a.w << 16);
  i.u[1] = (a.z >> 16)     | (a.w & 0xFFFF0000u);
  r.u[2] = (b.x & 0xFFFFu) | (b.y << 16);
  i.u[2] = (b.x >> 16)     | (b.y & 0xFFFF0000u);
  r.u[3] = (b.z & 0xFFFFu) | (b.w << 16);
  i.u[3] = (b.z >> 16)     | (b.w & 0xFFFF0000u);
  re = r.v; im = i.v;
}

// ---- cast params: B,C,D -> bf16 (Cim negated); A -> swizzled-lane-order fp32
__global__ __launch_bounds__(256) void k_params(
    const float* Are, const float* Aim, const float* Bre, const float* Bim,
    const float* Cre, const float* Cim, const float* D,
    unsigned short* bre, unsigned short* bim, unsigned short* cre,
    unsigned short* cimn, unsigned short* dbf, float* atre, float* atim) {
  int idx = blockIdx.x * 256 + threadIdx.x;
  int stride = gridDim.x * 256;
  for (int i = idx; i < N * U; i += stride) { bre[i] = f2bf(Bre[i]); bim[i] = f2bf(Bim[i]); }
  for (int i = idx; i < P * N; i += stride) { cre[i] = f2bf(Cre[i]); cimn[i] = f2bf(-Cim[i]); }
  for (int i = idx; i < P * U; i += stride) { dbf[i] = f2bf(D[i]); }
  for (int i = idx; i < NK; i += stride) {
    // i is the STORAGE index; invert zswz (XOR is involutive)
    int k = i >> 8, r = i & 255;
    int n8 = (r >> 3) ^ (k & 7);
    int j  = (r & 7) ^ (((k >> 3) & 1) << 2);
    int n = n8 * 8 + j;
    atre[i] = Are[n * K + k];
    atim[i] = Aim[n * K + k];
  }
}

// ---- x (T,U,K) fp32 -> xT (T,K,U) bf16 (u contiguous), via LDS transpose
__global__ __launch_bounds__(256) void k_castx(const float* x, unsigned* xTu) {
  __shared__ float lds[U * 33];            // rows u, padded stride 33
  int t = blockIdx.x, tid = threadIdx.x;
  const float* xt = x + (size_t)t * (U * K);
#pragma unroll
  for (int it = 0; it < 16; it++) {
    int idx = it * 256 + tid;
    int u = idx >> 5, k = idx & 31;
    lds[u * 33 + k] = xt[idx];
  }
  __syncthreads();
  unsigned* dst = xTu + (size_t)t * (K * U / 2);
#pragma unroll
  for (int it = 0; it < 8; it++) {
    int k = it * 4 + (tid >> 6);
    int up = tid & 63;
    float f0 = lds[(2 * up) * 33 + k];
    float f1 = lds[(2 * up + 1) * 33 + k];
    dst[k * 64 + up] = (unsigned)f2bf(f0) | ((unsigned)f2bf(f1) << 16);
  }
}

// ---- zbuf[tl][swz(k,n)] (packed bf16 re|im) = B @ x_t.  TB timesteps/block,
//      B fragments register-resident.  waves_per_eu(1,4): min=1 raises the
//      VGPR budget so the allocator keeps the 128-reg B fragment set resident
//      (at (2,2) it capped ~120 arch and rematerialized).  256-thread block
//      needs only 1 wave/EU for residency, so min=1 is always schedulable.
__global__ __launch_bounds__(256)
__attribute__((amdgpu_waves_per_eu(1, 4)))
void k_bgemm(const unsigned short* xT, const unsigned short* bre,
             const unsigned short* bim, unsigned* zbuf, int t0) {
  int blk = blockIdx.x, tid = threadIdx.x;
  int w = tid >> 6, l = tid & 63, lq = l >> 4, lr = l & 15;
  short8 Bf_re[4][4], Bf_im[4][4];   // [s][nt] -> 128 VGPRs
#pragma unroll
  for (int s = 0; s < 4; s++)
#pragma unroll
    for (int nt = 0; nt < 4; nt++) {
      int n0 = (w * 4 + nt) * 16;
      Bf_re[s][nt] = ld8(bre + (n0 + lr) * U + s * 32 + lq * 8);
      Bf_im[s][nt] = ld8(bim + (n0 + lr) * U + s * 32 + lq * 8);
    }
#pragma unroll
  for (int tl = 0; tl < TB; tl++) {
    int tloc = blk * TB + tl;
    const unsigned short* xrow = xT + (size_t)(t0 + tloc) * (K * U);
    short8 af[4][2];
#pragma unroll
    for (int s = 0; s < 4; s++) {
      af[s][0] = ld8(xrow + lr * U + s * 32 + lq * 8);
      af[s][1] = ld8(xrow + (16 + lr) * U + s * 32 + lq * 8);
    }
    f32x4 accre[2][4], accim[2][4];
#pragma unroll
    for (int a = 0; a < 2; a++)
#pragma unroll
      for (int b = 0; b < 4; b++) { accre[a][b] = (f32x4)0.f; accim[a][b] = (f32x4)0.f; }
#pragma unroll
    for (int s = 0; s < 4; s++)
#pragma unroll
      for (int nt = 0; nt < 4; nt++)
#pragma unroll
        for (int mt = 0; mt < 2; mt++) {
          accre[mt][nt] = __builtin_amdgcn_mfma_f32_16x16x32_bf16(af[s][mt], Bf_re[s][nt], accre[mt][nt], 0, 0, 0);
          accim[mt][nt] = __builtin_amdgcn_mfma_f32_16x16x32_bf16(af[s][mt], Bf_im[s][nt], accim[mt][nt], 0, 0, 0);
        }
    unsigned* dst = zbuf + (size_t)tloc * NK;
#pragma unroll
    for (int mt = 0; mt < 2; mt++)
#pragma unroll
      for (int nt = 0; nt < 4; nt++) {
        int n0 = (w * 4 + nt) * 16;
#pragma unroll
        for (int r = 0; r < 4; r++) {
          int krow = mt * 16 + lq * 4 + r;
          dst[zswz(krow, n0 + lr)] =
              (unsigned)f2bf(accre[mt][nt][r]) | ((unsigned)f2bf(accim[mt][nt][r]) << 16);
        }
      }
  }
}

// ---- pass A: chunk-local scan (16 steps), keep only chunk-end value
__global__ __launch_bounds__(256) void k_scanA(const unsigned* zbuf, const float* atre,
                                               const float* atim, float2* cend, int c0) {
  int bid = blockIdx.x;
  int cl = bid >> 5;                       // local chunk index within stage
  int lane = (bid & 31) * 256 + threadIdx.x;
  float ar = atre[lane], ai = atim[lane];
  float sr = 0.f, si = 0.f;
  const unsigned* src = zbuf + (size_t)cl * CL * NK + lane;
#pragma unroll 8
  for (int i = 0; i < CL; i++) {
    unsigned v = src[(size_t)i * NK];
    float ur = bf2f((unsigned short)(v & 0xFFFFu));
    float ui = bf2f((unsigned short)(v >> 16));
    float nr = ar * sr - ai * si + ur;
    float ni = ar * si + ai * sr + ui;
    sr = nr; si = ni;
  }
  cend[(size_t)(c0 + cl) * NK + lane] = make_float2(sr, si);
}

// ---- carry hierarchy over cend[NCH][NK] (storage-lane order, A = atre/atim).
// g-level: aggregate of each group of 8 chunk-ends, multiplier a^CL (= a^16)
__global__ __launch_bounds__(256) void k_carryg(const float2* cend, const float* atre,
                                                const float* atim, float2* gagg) {
  int bid = blockIdx.x;
  int g = bid >> 5;
  int lane = (bid & 31) * 256 + threadIdx.x;
  float pr = atre[lane], pi = atim[lane];
#pragma unroll
  for (int i = 0; i < 4; i++) csq(pr, pi);   // a^16
  float agr = 0.f, agi = 0.f;
#pragma unroll
  for (int j = 0; j < 8; j++) {
    float2 e = cend[(size_t)(g * 8 + j) * NK + lane];
    float nr = pr * agr - pi * agi + e.x;
    float ni = pr * agi + pi * agr + e.y;
    agr = nr; agi = ni;
  }
  gagg[(size_t)g * NK + lane] = make_float2(agr, agi);
}

// b-level: exclusive scan across NG groups, multiplier a^(CL*8) = a^128; in place
__global__ __launch_bounds__(256) void k_carryb(float2* gagg, const float* atre,
                                                const float* atim) {
  int lane = blockIdx.x * 256 + threadIdx.x;
  float pr = atre[lane], pi = atim[lane];
#pragma unroll
  for (int i = 0; i < 7; i++) csq(pr, pi);   // a^128
  float cr = 0.f, ci = 0.f;
  for (int gg = 0; gg < NG / 8; gg++) {
    float2 buf[8];
#pragma unroll
    for (int j = 0; j < 8; j++) buf[j] = gagg[(size_t)(gg * 8 + j) * NK + lane];
#pragma unroll
    for (int j = 0; j < 8; j++) {
      gagg[(size_t)(gg * 8 + j) * NK + lane] = make_float2(cr, ci);
      float nr = pr * cr - pi * ci + buf[j].x;
      float ni = pr * ci + pi * cr + buf[j].y;
      cr = nr; ci = ni;
    }
  }
}

// f-level: expand group carries to per-chunk carry-ins; cend -> carry-in, in place
__global__ __launch_bounds__(256) void k_carryf(float2* cend, const float* atre,
                                                const float* atim, const float2* gagg) {
  int bid = blockIdx.x;
  int g = bid >> 5;
  int lane = (bid & 31) * 256 + threadIdx.x;
  float pr = atre[lane], pi = atim[lane];
#pragma unroll
  for (int i = 0; i < 4; i++) csq(pr, pi);   // a^16
  float2 c = gagg[(size_t)g * NK + lane];
  float cr = c.x, ci = c.y;
#pragma unroll
  for (int j = 0; j < 8; j++) {
    size_t off = (size_t)(g * 8 + j) * NK + lane;
    float2 e = cend[off];
    cend[off] = make_float2(cr, ci);
    float nr = pr * cr - pi * ci + e.x;
    float ni = pr * ci + pi * cr + e.y;
    cr = nr; ci = ni;
  }
}

// ---- fused replay-scan + output, 3-slice LDS ring, ONE raw barrier per
//      timestep, counted vmcnt (never drained):
//        iter t: xfr(t) loads | vmcnt(20) -> own DMA(t) done |
//                scan buf[t%3] (own 16B regions = own dma16 lanes) |
//                lgkmcnt(0); s_barrier  (scan visible; old readers drained) |
//                issue DMA(t+2) -> buf[(t+2)%3] | MFMA from buf[t%3] | stores
//      waves_per_eu(1,4): min=1 raises the VGPR budget so Cf/Df/ar/ai stay
//      register-resident instead of being rematerialized from L2 every
//      timestep (the R4 VGPR=120 stall).  Flat workgroup size 512 still
//      caps usage at 256/wave, so the 8-wave block remains schedulable.
__global__ __launch_bounds__(512)
__attribute__((amdgpu_waves_per_eu(1, 4)))
void k_scout(const unsigned* zbuf, const float* atre, const float* atim,
             const float2* cend,
             const unsigned short* cre, const unsigned short* cimn,
             const unsigned short* dbf, const unsigned short* xT,
             float* out, int t0, int gc0) {
  __shared__ unsigned ldsz[3][NK];   // 3 x 32 KB ring
  int blk = blockIdx.x, tid = threadIdx.x;
  int w = tid >> 6, l = tid & 63, lq = l >> 4, lr = l & 15;
  int h = (lr >> 3) & 1;
  // hoist C/D fragments: wave w owns p-tile w*16
  short8 Cf_re[8], Cf_im[8];         // 64 VGPRs
#pragma unroll
  for (int s = 0; s < 8; s++) {
    int p = w * 16 + lr;
    Cf_re[s] = ld8(cre  + p * N + s * 32 + lq * 8);
    Cf_im[s] = ld8(cimn + p * N + s * 32 + lq * 8);
  }
  short8 Df[4];                      // 16 VGPRs
#pragma unroll
  for (int s = 0; s < 4; s++) {
    int p = w * 16 + lr;
    Df[s] = ld8(dbf + p * U + s * 32 + lq * 8);
  }
  // scan state + A for this thread's 16 storage dwords (it*2048 + tid*4 + j)
  float ar[16], ai[16], sr[16], si[16];
  int gc = gc0 + blk;
#pragma unroll
  for (int it = 0; it < 4; it++)
#pragma unroll
    for (int j = 0; j < 4; j++) {
      int idx = it * 2048 + tid * 4 + j;
      int e = it * 4 + j;
      ar[e] = atre[idx]; ai[e] = atim[idx];
      float2 c0 = cend[(size_t)gc * NK + idx];   // carry-in (exclusive)
      sr[e] = c0.x; si[e] = c0.y;
    }
  // prologue: DMA slices 0 and 1 into ring buffers 0,1
  const unsigned* zch = zbuf + (size_t)(blk * CL) * NK;
#pragma unroll
  for (int it = 0; it < 4; it++)
    dma16(zch + it * 2048 + tid * 4, &ldsz[0][it * 2048 + tid * 4]);
#pragma unroll
  for (int it = 0; it < 4; it++)
    dma16(zch + NK + it * 2048 + tid * 4, &ldsz[1][it * 2048 + tid * 4]);

  int bc = 0;                        // ring slot of slice tl
  for (int tl = 0; tl < CL; tl++) {
    int t = t0 + blk * CL + tl;      // global t
    // x fragments first (counted in the vmcnt budget below)
    const unsigned short* xt = xT + (size_t)t * (K * U);
    short8 xfr[4][2];
#pragma unroll
    for (int s = 0; s < 4; s++)
#pragma unroll
      for (int kt = 0; kt < 2; kt++)
        xfr[s][kt] = ld8(xt + (kt * 16 + lr) * U + s * 32 + lq * 8);
    // own DMA(tl) complete; allow {xfr 8, stores(t-1) 8, DMA(tl+1) 4} in flight
    if (tl == 0) { asm volatile("s_waitcnt vmcnt(12)" ::: "memory"); }
    else         { asm volatile("s_waitcnt vmcnt(20)" ::: "memory"); }
    // ---- scan: update this thread's 16 dwords of slice tl in place
    unsigned* zl = &ldsz[bc][0];
#pragma unroll
    for (int it = 0; it < 4; it++) {
      unsigned* p4 = zl + it * 2048 + tid * 4;
      uint4 v = *reinterpret_cast<const uint4*>(p4);
      unsigned d0 = v.x, d1 = v.y, d2 = v.z, d3 = v.w;
#pragma unroll
      for (int j = 0; j < 4; j++) {
        unsigned dv = (j == 0) ? d0 : (j == 1) ? d1 : (j == 2) ? d2 : d3;
        int e = it * 4 + j;
        float ur = bf2f((unsigned short)(dv & 0xFFFFu));
        float ui = bf2f((unsigned short)(dv >> 16));
        float nr = ar[e] * sr[e] - ai[e] * si[e] + ur;
        float ni = ar[e] * si[e] + ai[e] * sr[e] + ui;
        sr[e] = nr; si[e] = ni;
        dv = (unsigned)f2bf(nr) | ((unsigned)f2bf(ni) << 16);
        if (j == 0) d0 = dv; else if (j == 1) d1 = dv; else if (j == 2) d2 = dv; else d3 = dv;
      }
      uint4 o; o.x = d0; o.y = d1; o.z = d2; o.w = d3;
      *reinterpret_cast<uint4*>(p4) = o;
    }
    // scan writes drained, then single cross-wave barrier
    asm volatile("s_waitcnt lgkmcnt(0)" ::: "memory");
    __builtin_amdgcn_s_barrier();
    __builtin_amdgcn_sched_barrier(0);
    // async prefetch slice tl+2 into ring slot (bc+2)%3 (readers drained above)
    if (tl + 2 < CL) {
      int bn = bc + 2; if (bn >= 3) bn -= 3;
      const unsigned* zn = zbuf + (size_t)(blk * CL + tl + 2) * NK;
#pragma unroll
      for (int it = 0; it < 4; it++)
        dma16(zn + it * 2048 + tid * 4, &ldsz[bn][it * 2048 + tid * 4]);
    }
    // ---- output MFMAs from the states slice
    f32x4 acc[2];
    acc[0] = (f32x4)0.f; acc[1] = (f32x4)0.f;
    const unsigned* zs = &ldsz[bc][0];
#pragma unroll
    for (int s = 0; s < 8; s++) {
      short8 bfr[2], bfi[2];
#pragma unroll
      for (int kt = 0; kt < 2; kt++) {
        int k = kt * 16 + lr;
        int n8 = s * 4 + lq;
        const uint4* qp = reinterpret_cast<const uint4*>(zs + k * 256 + ((n8 ^ (k & 7)) << 3));
        uint4 a = qp[h], b = qp[h ^ 1];
        unpackAB(a, b, bfr[kt], bfi[kt]);
      }
#pragma unroll
      for (int kt = 0; kt < 2; kt++) {
        acc[kt] = __builtin_amdgcn_mfma_f32_16x16x32_bf16(Cf_re[s], bfr[kt], acc[kt], 0, 0, 0);
        acc[kt] = __builtin_amdgcn_mfma_f32_16x16x32_bf16(Cf_im[s], bfi[kt], acc[kt], 0, 0, 0);
      }
    }
#pragma unroll
    for (int s = 0; s < 4; s++)
#pragma unroll
      for (int kt = 0; kt < 2; kt++)
        acc[kt] = __builtin_amdgcn_mfma_f32_16x16x32_bf16(Df[s], xfr[s][kt], acc[kt], 0, 0, 0);
    float* ot = out + (size_t)t * (P * K);
#pragma unroll
    for (int kt = 0; kt < 2; kt++)
#pragma unroll
      for (int r = 0; r < 4; r++) {
        int p = w * 16 + lq * 4 + r;
        int k = kt * 16 + lr;
        ot[p * K + k] = acc[kt][r];
      }
    bc = bc + 1; if (bc >= 3) bc -= 3;
  }
}

}  // namespace

extern "C" void kernel_launch(void* const* d_in, const int* in_sizes, int n_in,
                              void* d_out, int out_size, void* d_ws, size_t ws_size,
                              hipStream_t stream) {
  const float* x   = (const float*)d_in[0];
  const float* Are = (const float*)d_in[1];
  const float* Aim = (const float*)d_in[2];
  const float* Bre = (const float*)d_in[3];
  const float* Bim = (const float*)d_in[4];
  const float* Cre = (const float*)d_in[5];
  const float* Cim = (const float*)d_in[6];
  const float* D   = (const float*)d_in[7];
  float* out = (float*)d_out;

  auto al = [](size_t x_) { return (x_ + 255) & ~(size_t)255; };
  const size_t fixed = al((size_t)T * K * U * 2)      // xT
                     + al((size_t)NCH * NK * 8)       // cend
                     + al((size_t)NG * NK * 8)        // gagg
                     + 2 * al((size_t)N * U * 2)      // bre,bim
                     + 2 * al((size_t)P * N * 2)      // cre,cimn
                     + al((size_t)P * U * 2)          // dbf
                     + 2 * al((size_t)NK * 4);        // atre,atim
  int S = 64;
  for (int s : {1, 2, 4, 8, 16, 32, 64}) {
    if (fixed + al((size_t)(T / s) * NK * 4) <= ws_size) { S = s; break; }
  }
  const int TS = T / S;        // timesteps per stage
  const int CS = NCH / S;      // chunks per stage

  char* w = (char*)d_ws;
  auto alloc = [&](size_t bytes) { void* p = (void*)w; w += (bytes + 255) & ~(size_t)255; return p; };
  unsigned* zbuf       = (unsigned*)alloc((size_t)TS * NK * 4);
  unsigned* xTu        = (unsigned*)alloc((size_t)T * K * U * 2);
  float2* cend         = (float2*)alloc((size_t)NCH * NK * 8);
  float2* gagg         = (float2*)alloc((size_t)NG * NK * 8);
  unsigned short* bre  = (unsigned short*)alloc((size_t)N * U * 2);
  unsigned short* bim  = (unsigned short*)alloc((size_t)N * U * 2);
  unsigned short* cre  = (unsigned short*)alloc((size_t)P * N * 2);
  unsigned short* cimn = (unsigned short*)alloc((size_t)P * N * 2);
  unsigned short* dbf  = (unsigned short*)alloc((size_t)P * U * 2);
  float* atre          = (float*)alloc((size_t)NK * 4);
  float* atim          = (float*)alloc((size_t)NK * 4);

  k_params<<<64, 256, 0, stream>>>(Are, Aim, Bre, Bim, Cre, Cim, D,
                                   bre, bim, cre, cimn, dbf, atre, atim);
  k_castx<<<T, 256, 0, stream>>>(x, xTu);

  const unsigned short* xT16 = (const unsigned short*)xTu;
  // pass 1: chunk-local ends (16-step chunks)
  for (int q = 0; q < S; q++) {
    k_bgemm<<<TS / TB, 256, 0, stream>>>(xT16, bre, bim, zbuf, q * TS);
    k_scanA<<<CS * 32, 256, 0, stream>>>(zbuf, atre, atim, cend, q * CS);
  }
  // cross-chunk carries, hierarchical (groups of 8 chunks, then NG groups)
  k_carryg<<<NG * 32, 256, 0, stream>>>(cend, atre, atim, gagg);
  k_carryb<<<NK / 256, 256, 0, stream>>>(gagg, atre, atim);
  k_carryf<<<NG * 32, 256, 0, stream>>>(cend, atre, atim, gagg);
  // pass 2: fused replay-scan + output (states never touch HBM)
  for (int q = 0; q < S; q++) {
    if (S > 1)  // zbuf was overwritten by later stages; recompute
      k_bgemm<<<TS / TB, 256, 0, stream>>>(xT16, bre, bim, zbuf, q * TS);
    k_scout<<<TS / CL, 512, 0, stream>>>(zbuf, atre, atim, cend,
                                         cre, cimn, dbf, xT16, out, q * TS, q * CS);
  }
}

// Round 8
// 264.023 us; speedup vs baseline: 1.8204x; 1.0313x over previous
//
#include <hip/hip_runtime.h>
#include <hip/hip_bf16.h>

namespace {

constexpr int T = 4096, N = 256, U = 128, K = 32, P = 128;
constexpr int NK = N * K;           // 8192 scan lanes
constexpr int CL = 16;              // chunk length = k_scout block timestep span
constexpr int NCH = T / CL;         // 256 chunks total
constexpr int NG = NCH / 8;         // 32 carry groups (8 chunks each)
constexpr int TB = 8;               // timesteps per block in bgemm

typedef __attribute__((ext_vector_type(8))) short short8;   // 8 bf16
typedef __attribute__((ext_vector_type(4))) float f32x4;
typedef __attribute__((address_space(3))) unsigned lds_u32;
typedef __attribute__((address_space(1))) const unsigned glb_u32;

__device__ __forceinline__ unsigned short f2bf(float f) {
  union { float f; unsigned u; } v; v.f = f;
  unsigned r = v.u + 0x7FFFu + ((v.u >> 16) & 1u);   // RNE
  return (unsigned short)(r >> 16);
}
__device__ __forceinline__ float bf2f(unsigned short s) {
  union { unsigned u; float f; } v; v.u = ((unsigned)s) << 16;
  return v.f;
}
__device__ __forceinline__ short8 ld8(const unsigned short* p) {
  return *reinterpret_cast<const short8*>(p);
}
// async global->LDS, 16 B per lane; LDS dest = wave-uniform base + lane*16
__device__ __forceinline__ void dma16(const unsigned* g, unsigned* l) {
  __builtin_amdgcn_global_load_lds((glb_u32*)g, (lds_u32*)l, 16, 0, 0);
}
__device__ __forceinline__ void csq(float& pr, float& pi) {  // complex square
  float nr = pr * pr - pi * pi, ni = 2.f * pr * pi; pr = nr; pi = ni;
}

// Swizzled storage index (dwords) of logical element (k,n) within a t-slice.
__device__ __forceinline__ int zswz(int k, int n) {
  int n8 = n >> 3, j = n & 7;
  return k * 256 + ((n8 ^ (k & 7)) << 3) + (j ^ (((k >> 3) & 1) << 2));
}

// a = dwords for n8*8+{0..3}, b = n8*8+{4..7}; each dword packs (re|im) bf16
__device__ __forceinline__ void unpackAB(uint4 a, uint4 b, short8& re, short8& im) {
  union { short8 v; unsigned u[4]; } r, i;
  r.u[0] = (a.x & 0xFFFFu) | (a.y << 16);
  i.u[0] = (a.x >> 16)     | (a.y & 0xFFFF0000u);
  r.u[1] = (a.z & 0xFFFFu) | (a.w << 16);
  i.u[1] = (a.z >> 16)     | (a.w & 0xFFFF0000u);
  r.u[2] = (b.x & 0xFFFFu) | (b.y << 16);
  i.u[2] = (b.x >> 16)     | (b.y & 0xFFFF0000u);
  r.u[3] = (b.z & 0xFFFFu) | (b.w << 16);
  i.u[3] = (b.z >> 16)     | (b.w & 0xFFFF0000u);
  re = r.v; im = i.v;
}

// ---- cast params: B,C,D -> bf16 (Cim negated); A -> swizzled-lane-order fp32
__global__ __launch_bounds__(256) void k_params(
    const float* Are, const float* Aim, const float* Bre, const float* Bim,
    const float* Cre, const float* Cim, const float* D,
    unsigned short* bre, unsigned short* bim, unsigned short* cre,
    unsigned short* cimn, unsigned short* dbf, float* atre, float* atim) {
  int idx = blockIdx.x * 256 + threadIdx.x;
  int stride = gridDim.x * 256;
  for (int i = idx; i < N * U; i += stride) { bre[i] = f2bf(Bre[i]); bim[i] = f2bf(Bim[i]); }
  for (int i = idx; i < P * N; i += stride) { cre[i] = f2bf(Cre[i]); cimn[i] = f2bf(-Cim[i]); }
  for (int i = idx; i < P * U; i += stride) { dbf[i] = f2bf(D[i]); }
  for (int i = idx; i < NK; i += stride) {
    // i is the STORAGE index; invert zswz (XOR is involutive)
    int k = i >> 8, r = i & 255;
    int n8 = (r >> 3) ^ (k & 7);
    int j  = (r & 7) ^ (((k >> 3) & 1) << 2);
    int n = n8 * 8 + j;
    atre[i] = Are[n * K + k];
    atim[i] = Aim[n * K + k];
  }
}

// ---- x (T,U,K) fp32 -> xT (T,K,U) bf16 (u contiguous), via LDS transpose
__global__ __launch_bounds__(256) void k_castx(const float* x, unsigned* xTu) {
  __shared__ float lds[U * 33];            // rows u, padded stride 33
  int t = blockIdx.x, tid = threadIdx.x;
  const float* xt = x + (size_t)t * (U * K);
#pragma unroll
  for (int it = 0; it < 16; it++) {
    int idx = it * 256 + tid;
    int u = idx >> 5, k = idx & 31;
    lds[u * 33 + k] = xt[idx];
  }
  __syncthreads();
  unsigned* dst = xTu + (size_t)t * (K * U / 2);
#pragma unroll
  for (int it = 0; it < 8; it++) {
    int k = it * 4 + (tid >> 6);
    int up = tid & 63;
    float f0 = lds[(2 * up) * 33 + k];
    float f1 = lds[(2 * up + 1) * 33 + k];
    dst[k * 64 + up] = (unsigned)f2bf(f0) | ((unsigned)f2bf(f1) << 16);
  }
}

// ---- zbuf[tl][swz(k,n)] (packed bf16 re|im) = B @ x_t.  TB timesteps/block,
//      B fragments register-resident.  (2,2): R7's A/B showed bgemm needs the
//      2-block/CU residency more than extra registers (at (1,4): VGPR 140,
//      occupancy 10.8%, 89.8 us; at (2,2): ~60-65 us).
__global__ __launch_bounds__(256)
__attribute__((amdgpu_waves_per_eu(2, 2)))
void k_bgemm(const unsigned short* xT, const unsigned short* bre,
             const unsigned short* bim, unsigned* zbuf, int t0) {
  int blk = blockIdx.x, tid = threadIdx.x;
  int w = tid >> 6, l = tid & 63, lq = l >> 4, lr = l & 15;
  short8 Bf_re[4][4], Bf_im[4][4];   // [s][nt] -> 128 VGPRs
#pragma unroll
  for (int s = 0; s < 4; s++)
#pragma unroll
    for (int nt = 0; nt < 4; nt++) {
      int n0 = (w * 4 + nt) * 16;
      Bf_re[s][nt] = ld8(bre + (n0 + lr) * U + s * 32 + lq * 8);
      Bf_im[s][nt] = ld8(bim + (n0 + lr) * U + s * 32 + lq * 8);
    }
#pragma unroll
  for (int tl = 0; tl < TB; tl++) {
    int tloc = blk * TB + tl;
    const unsigned short* xrow = xT + (size_t)(t0 + tloc) * (K * U);
    short8 af[4][2];
#pragma unroll
    for (int s = 0; s < 4; s++) {
      af[s][0] = ld8(xrow + lr * U + s * 32 + lq * 8);
      af[s][1] = ld8(xrow + (16 + lr) * U + s * 32 + lq * 8);
    }
    f32x4 accre[2][4], accim[2][4];
#pragma unroll
    for (int a = 0; a < 2; a++)
#pragma unroll
      for (int b = 0; b < 4; b++) { accre[a][b] = (f32x4)0.f; accim[a][b] = (f32x4)0.f; }
#pragma unroll
    for (int s = 0; s < 4; s++)
#pragma unroll
      for (int nt = 0; nt < 4; nt++)
#pragma unroll
        for (int mt = 0; mt < 2; mt++) {
          accre[mt][nt] = __builtin_amdgcn_mfma_f32_16x16x32_bf16(af[s][mt], Bf_re[s][nt], accre[mt][nt], 0, 0, 0);
          accim[mt][nt] = __builtin_amdgcn_mfma_f32_16x16x32_bf16(af[s][mt], Bf_im[s][nt], accim[mt][nt], 0, 0, 0);
        }
    unsigned* dst = zbuf + (size_t)tloc * NK;
#pragma unroll
    for (int mt = 0; mt < 2; mt++)
#pragma unroll
      for (int nt = 0; nt < 4; nt++) {
        int n0 = (w * 4 + nt) * 16;
#pragma unroll
        for (int r = 0; r < 4; r++) {
          int krow = mt * 16 + lq * 4 + r;
          dst[zswz(krow, n0 + lr)] =
              (unsigned)f2bf(accre[mt][nt][r]) | ((unsigned)f2bf(accim[mt][nt][r]) << 16);
        }
      }
  }
}

// ---- pass A: chunk-local scan (16 steps), keep only chunk-end value
__global__ __launch_bounds__(256) void k_scanA(const unsigned* zbuf, const float* atre,
                                               const float* atim, float2* cend, int c0) {
  int bid = blockIdx.x;
  int cl = bid >> 5;                       // local chunk index within stage
  int lane = (bid & 31) * 256 + threadIdx.x;
  float ar = atre[lane], ai = atim[lane];
  float sr = 0.f, si = 0.f;
  const unsigned* src = zbuf + (size_t)cl * CL * NK + lane;
#pragma unroll 8
  for (int i = 0; i < CL; i++) {
    unsigned v = src[(size_t)i * NK];
    float ur = bf2f((unsigned short)(v & 0xFFFFu));
    float ui = bf2f((unsigned short)(v >> 16));
    float nr = ar * sr - ai * si + ur;
    float ni = ar * si + ai * sr + ui;
    sr = nr; si = ni;
  }
  cend[(size_t)(c0 + cl) * NK + lane] = make_float2(sr, si);
}

// ---- carry hierarchy over cend[NCH][NK] (storage-lane order, A = atre/atim).
// g-level: aggregate of each group of 8 chunk-ends, multiplier a^CL (= a^16)
__global__ __launch_bounds__(256) void k_carryg(const float2* cend, const float* atre,
                                                const float* atim, float2* gagg) {
  int bid = blockIdx.x;
  int g = bid >> 5;
  int lane = (bid & 31) * 256 + threadIdx.x;
  float pr = atre[lane], pi = atim[lane];
#pragma unroll
  for (int i = 0; i < 4; i++) csq(pr, pi);   // a^16
  float agr = 0.f, agi = 0.f;
#pragma unroll
  for (int j = 0; j < 8; j++) {
    float2 e = cend[(size_t)(g * 8 + j) * NK + lane];
    float nr = pr * agr - pi * agi + e.x;
    float ni = pr * agi + pi * agr + e.y;
    agr = nr; agi = ni;
  }
  gagg[(size_t)g * NK + lane] = make_float2(agr, agi);
}

// b-level: exclusive scan across NG groups, multiplier a^(CL*8) = a^128; in place
__global__ __launch_bounds__(256) void k_carryb(float2* gagg, const float* atre,
                                                const float* atim) {
  int lane = blockIdx.x * 256 + threadIdx.x;
  float pr = atre[lane], pi = atim[lane];
#pragma unroll
  for (int i = 0; i < 7; i++) csq(pr, pi);   // a^128
  float cr = 0.f, ci = 0.f;
  for (int gg = 0; gg < NG / 8; gg++) {
    float2 buf[8];
#pragma unroll
    for (int j = 0; j < 8; j++) buf[j] = gagg[(size_t)(gg * 8 + j) * NK + lane];
#pragma unroll
    for (int j = 0; j < 8; j++) {
      gagg[(size_t)(gg * 8 + j) * NK + lane] = make_float2(cr, ci);
      float nr = pr * cr - pi * ci + buf[j].x;
      float ni = pr * ci + pi * cr + buf[j].y;
      cr = nr; ci = ni;
    }
  }
}

// f-level: expand group carries to per-chunk carry-ins; cend -> carry-in, in place
__global__ __launch_bounds__(256) void k_carryf(float2* cend, const float* atre,
                                                const float* atim, const float2* gagg) {
  int bid = blockIdx.x;
  int g = bid >> 5;
  int lane = (bid & 31) * 256 + threadIdx.x;
  float pr = atre[lane], pi = atim[lane];
#pragma unroll
  for (int i = 0; i < 4; i++) csq(pr, pi);   // a^16
  float2 c = gagg[(size_t)g * NK + lane];
  float cr = c.x, ci = c.y;
#pragma unroll
  for (int j = 0; j < 8; j++) {
    size_t off = (size_t)(g * 8 + j) * NK + lane;
    float2 e = cend[off];
    cend[off] = make_float2(cr, ci);
    float nr = pr * cr - pi * ci + e.x;
    float ni = pr * ci + pi * cr + e.y;
    cr = nr; ci = ni;
  }
}

// ---- fused replay-scan + output, 3-slice LDS ring, ONE raw barrier per
//      timestep, counted vmcnt (never drained):
//        iter t: xfr(t) loads | vmcnt(20) -> own DMA(t) done |
//                scan buf[t%3] (own 16B regions = own dma16 lanes) |
//                lgkmcnt(0); s_barrier  (scan visible; old readers drained) |
//                issue DMA(t+2) -> buf[(t+2)%3] | MFMA from buf[t%3] | stores
//      waves_per_eu(1,4): min=1 raises the VGPR budget so Cf/Df/ar/ai stay
//      register-resident instead of being rematerialized from L2 every
//      timestep (R7 A/B: scout improved ~72 -> ~55 with this attribute).
__global__ __launch_bounds__(512)
__attribute__((amdgpu_waves_per_eu(1, 4)))
void k_scout(const unsigned* zbuf, const float* atre, const float* atim,
             const float2* cend,
             const unsigned short* cre, const unsigned short* cimn,
             const unsigned short* dbf, const unsigned short* xT,
             float* out, int t0, int gc0) {
  __shared__ unsigned ldsz[3][NK];   // 3 x 32 KB ring
  int blk = blockIdx.x, tid = threadIdx.x;
  int w = tid >> 6, l = tid & 63, lq = l >> 4, lr = l & 15;
  int h = (lr >> 3) & 1;
  // hoist C/D fragments: wave w owns p-tile w*16
  short8 Cf_re[8], Cf_im[8];         // 64 VGPRs
#pragma unroll
  for (int s = 0; s < 8; s++) {
    int p = w * 16 + lr;
    Cf_re[s] = ld8(cre  + p * N + s * 32 + lq * 8);
    Cf_im[s] = ld8(cimn + p * N + s * 32 + lq * 8);
  }
  short8 Df[4];                      // 16 VGPRs
#pragma unroll
  for (int s = 0; s < 4; s++) {
    int p = w * 16 + lr;
    Df[s] = ld8(dbf + p * U + s * 32 + lq * 8);
  }
  // scan state + A for this thread's 16 storage dwords (it*2048 + tid*4 + j)
  float ar[16], ai[16], sr[16], si[16];
  int gc = gc0 + blk;
#pragma unroll
  for (int it = 0; it < 4; it++)
#pragma unroll
    for (int j = 0; j < 4; j++) {
      int idx = it * 2048 + tid * 4 + j;
      int e = it * 4 + j;
      ar[e] = atre[idx]; ai[e] = atim[idx];
      float2 c0 = cend[(size_t)gc * NK + idx];   // carry-in (exclusive)
      sr[e] = c0.x; si[e] = c0.y;
    }
  // prologue: DMA slices 0 and 1 into ring buffers 0,1
  const unsigned* zch = zbuf + (size_t)(blk * CL) * NK;
#pragma unroll
  for (int it = 0; it < 4; it++)
    dma16(zch + it * 2048 + tid * 4, &ldsz[0][it * 2048 + tid * 4]);
#pragma unroll
  for (int it = 0; it < 4; it++)
    dma16(zch + NK + it * 2048 + tid * 4, &ldsz[1][it * 2048 + tid * 4]);

  int bc = 0;                        // ring slot of slice tl
  for (int tl = 0; tl < CL; tl++) {
    int t = t0 + blk * CL + tl;      // global t
    // x fragments first (counted in the vmcnt budget below)
    const unsigned short* xt = xT + (size_t)t * (K * U);
    short8 xfr[4][2];
#pragma unroll
    for (int s = 0; s < 4; s++)
#pragma unroll
      for (int kt = 0; kt < 2; kt++)
        xfr[s][kt] = ld8(xt + (kt * 16 + lr) * U + s * 32 + lq * 8);
    // own DMA(tl) complete; allow {xfr 8, stores(t-1) 8, DMA(tl+1) 4} in flight
    if (tl == 0) { asm volatile("s_waitcnt vmcnt(12)" ::: "memory"); }
    else         { asm volatile("s_waitcnt vmcnt(20)" ::: "memory"); }
    // ---- scan: update this thread's 16 dwords of slice tl in place
    unsigned* zl = &ldsz[bc][0];
#pragma unroll
    for (int it = 0; it < 4; it++) {
      unsigned* p4 = zl + it * 2048 + tid * 4;
      uint4 v = *reinterpret_cast<const uint4*>(p4);
      unsigned d0 = v.x, d1 = v.y, d2 = v.z, d3 = v.w;
#pragma unroll
      for (int j = 0; j < 4; j++) {
        unsigned dv = (j == 0) ? d0 : (j == 1) ? d1 : (j == 2) ? d2 : d3;
        int e = it * 4 + j;
        float ur = bf2f((unsigned short)(dv & 0xFFFFu));
        float ui = bf2f((unsigned short)(dv >> 16));
        float nr = ar[e] * sr[e] - ai[e] * si[e] + ur;
        float ni = ar[e] * si[e] + ai[e] * sr[e] + ui;
        sr[e] = nr; si[e] = ni;
        dv = (unsigned)f2bf(nr) | ((unsigned)f2bf(ni) << 16);
        if (j == 0) d0 = dv; else if (j == 1) d1 = dv; else if (j == 2) d2 = dv; else d3 = dv;
      }
      uint4 o; o.x = d0; o.y = d1; o.z = d2; o.w = d3;
      *reinterpret_cast<uint4*>(p4) = o;
    }
    // scan writes drained, then single cross-wave barrier
    asm volatile("s_waitcnt lgkmcnt(0)" ::: "memory");
    __builtin_amdgcn_s_barrier();
    __builtin_amdgcn_sched_barrier(0);
    // async prefetch slice tl+2 into ring slot (bc+2)%3 (readers drained above)
    if (tl + 2 < CL) {
      int bn = bc + 2; if (bn >= 3) bn -= 3;
      const unsigned* zn = zbuf + (size_t)(blk * CL + tl + 2) * NK;
#pragma unroll
      for (int it = 0; it < 4; it++)
        dma16(zn + it * 2048 + tid * 4, &ldsz[bn][it * 2048 + tid * 4]);
    }
    // ---- output MFMAs from the states slice
    f32x4 acc[2];
    acc[0] = (f32x4)0.f; acc[1] = (f32x4)0.f;
    const unsigned* zs = &ldsz[bc][0];
#pragma unroll
    for (int s = 0; s < 8; s++) {
      short8 bfr[2], bfi[2];
#pragma unroll
      for (int kt = 0; kt < 2; kt++) {
        int k = kt * 16 + lr;
        int n8 = s * 4 + lq;
        const uint4* qp = reinterpret_cast<const uint4*>(zs + k * 256 + ((n8 ^ (k & 7)) << 3));
        uint4 a = qp[h], b = qp[h ^ 1];
        unpackAB(a, b, bfr[kt], bfi[kt]);
      }
#pragma unroll
      for (int kt = 0; kt < 2; kt++) {
        acc[kt] = __builtin_amdgcn_mfma_f32_16x16x32_bf16(Cf_re[s], bfr[kt], acc[kt], 0, 0, 0);
        acc[kt] = __builtin_amdgcn_mfma_f32_16x16x32_bf16(Cf_im[s], bfi[kt], acc[kt], 0, 0, 0);
      }
    }
#pragma unroll
    for (int s = 0; s < 4; s++)
#pragma unroll
      for (int kt = 0; kt < 2; kt++)
        acc[kt] = __builtin_amdgcn_mfma_f32_16x16x32_bf16(Df[s], xfr[s][kt], acc[kt], 0, 0, 0);
    float* ot = out + (size_t)t * (P * K);
#pragma unroll
    for (int kt = 0; kt < 2; kt++)
#pragma unroll
      for (int r = 0; r < 4; r++) {
        int p = w * 16 + lq * 4 + r;
        int k = kt * 16 + lr;
        ot[p * K + k] = acc[kt][r];
      }
    bc = bc + 1; if (bc >= 3) bc -= 3;
  }
}

}  // namespace

extern "C" void kernel_launch(void* const* d_in, const int* in_sizes, int n_in,
                              void* d_out, int out_size, void* d_ws, size_t ws_size,
                              hipStream_t stream) {
  const float* x   = (const float*)d_in[0];
  const float* Are = (const float*)d_in[1];
  const float* Aim = (const float*)d_in[2];
  const float* Bre = (const float*)d_in[3];
  const float* Bim = (const float*)d_in[4];
  const float* Cre = (const float*)d_in[5];
  const float* Cim = (const float*)d_in[6];
  const float* D   = (const float*)d_in[7];
  float* out = (float*)d_out;

  auto al = [](size_t x_) { return (x_ + 255) & ~(size_t)255; };
  const size_t fixed = al((size_t)T * K * U * 2)      // xT
                     + al((size_t)NCH * NK * 8)       // cend
                     + al((size_t)NG * NK * 8)        // gagg
                     + 2 * al((size_t)N * U * 2)      // bre,bim
                     + 2 * al((size_t)P * N * 2)      // cre,cimn
                     + al((size_t)P * U * 2)          // dbf
                     + 2 * al((size_t)NK * 4);        // atre,atim
  int S = 64;
  for (int s : {1, 2, 4, 8, 16, 32, 64}) {
    if (fixed + al((size_t)(T / s) * NK * 4) <= ws_size) { S = s; break; }
  }
  const int TS = T / S;        // timesteps per stage
  const int CS = NCH / S;      // chunks per stage

  char* w = (char*)d_ws;
  auto alloc = [&](size_t bytes) { void* p = (void*)w; w += (bytes + 255) & ~(size_t)255; return p; };
  unsigned* zbuf       = (unsigned*)alloc((size_t)TS * NK * 4);
  unsigned* xTu        = (unsigned*)alloc((size_t)T * K * U * 2);
  float2* cend         = (float2*)alloc((size_t)NCH * NK * 8);
  float2* gagg         = (float2*)alloc((size_t)NG * NK * 8);
  unsigned short* bre  = (unsigned short*)alloc((size_t)N * U * 2);
  unsigned short* bim  = (unsigned short*)alloc((size_t)N * U * 2);
  unsigned short* cre  = (unsigned short*)alloc((size_t)P * N * 2);
  unsigned short* cimn = (unsigned short*)alloc((size_t)P * N * 2);
  unsigned short* dbf  = (unsigned short*)alloc((size_t)P * U * 2);
  float* atre          = (float*)alloc((size_t)NK * 4);
  float* atim          = (float*)alloc((size_t)NK * 4);

  k_params<<<64, 256, 0, stream>>>(Are, Aim, Bre, Bim, Cre, Cim, D,
                                   bre, bim, cre, cimn, dbf, atre, atim);
  k_castx<<<T, 256, 0, stream>>>(x, xTu);

  const unsigned short* xT16 = (const unsigned short*)xTu;
  // pass 1: chunk-local ends (16-step chunks)
  for (int q = 0; q < S; q++) {
    k_bgemm<<<TS / TB, 256, 0, stream>>>(xT16, bre, bim, zbuf, q * TS);
    k_scanA<<<CS * 32, 256, 0, stream>>>(zbuf, atre, atim, cend, q * CS);
  }
  // cross-chunk carries, hierarchical (groups of 8 chunks, then NG groups)
  k_carryg<<<NG * 32, 256, 0, stream>>>(cend, atre, atim, gagg);
  k_carryb<<<NK / 256, 256, 0, stream>>>(gagg, atre, atim);
  k_carryf<<<NG * 32, 256, 0, stream>>>(cend, atre, atim, gagg);
  // pass 2: fused replay-scan + output (states never touch HBM)
  for (int q = 0; q < S; q++) {
    if (S > 1)  // zbuf was overwritten by later stages; recompute
      k_bgemm<<<TS / TB, 256, 0, stream>>>(xT16, bre, bim, zbuf, q * TS);
    k_scout<<<TS / CL, 512, 0, stream>>>(zbuf, atre, atim, cend,
                                         cre, cimn, dbf, xT16, out, q * TS, q * CS);
  }
}